// Round 4
// baseline (83.891 us; speedup 1.0000x reference)
//
#include <hip/hip_runtime.h>
#include <math.h>
#include <stdint.h>

#define N_SAMPLES 4096
#define S_DIM 512
#define A_DIM 16
#define ACT_DIM 20
#define E_DIM 64
#define M_DIM 320      // A*ACT
#define J_DIM 1216     // 1024 (W_h1) + 64 (W_b1) + 64 (W_hf) + 64 (W_v1)
#define JPAD 1280      // padded to 10 * 128 so staging never goes OOB

#define LOG2E 1.44269504088896f
#define LN2   0.69314718055995f

using bf16x8  = __attribute__((ext_vector_type(8))) short;
using f32x4   = __attribute__((ext_vector_type(4))) float;
using ushort8 = __attribute__((ext_vector_type(8))) unsigned short;

__device__ __forceinline__ unsigned short f2bf(float x) {  // RNE f32 -> bf16
    uint32_t u = __float_as_uint(x);
    u += 0x7fffu + ((u >> 16) & 1u);
    return (unsigned short)(u >> 16);
}
__device__ __forceinline__ float bf2f(unsigned short u) {
    return __uint_as_float(((uint32_t)u) << 16);
}

// ---------------------------------------------------------------- K0: convert
// Abf[4096][512] <- state ; Bbf[1280][512] <- {Wh1,Wb1,Whf,Wv1, zeros}
__global__ __launch_bounds__(256) void cvt_bf16(
    const float* __restrict__ S,
    const float* __restrict__ Wh1, const float* __restrict__ Wb1,
    const float* __restrict__ Whf, const float* __restrict__ Wv1,
    unsigned short* __restrict__ Abf, unsigned short* __restrict__ Bbf)
{
    const int A_QUADS = N_SAMPLES * S_DIM / 4;   // 524288
    const int B_QUADS = JPAD * S_DIM / 4;        // 163840
    int idx = blockIdx.x * 256 + threadIdx.x;
    if (idx < A_QUADS) {
        float4 v = reinterpret_cast<const float4*>(S)[idx];
        ushort4 o = { f2bf(v.x), f2bf(v.y), f2bf(v.z), f2bf(v.w) };
        reinterpret_cast<ushort4*>(Abf)[idx] = o;
    } else if (idx < A_QUADS + B_QUADS) {
        int q   = idx - A_QUADS;
        int row = q >> 7;          // 128 quads per 512-elem row
        int qc  = q & 127;
        ushort4 o = {0, 0, 0, 0};
        const float* src = nullptr;
        if (row < 1024)      src = Wh1 + (size_t)row * S_DIM;
        else if (row < 1088) src = Wb1 + (size_t)(row - 1024) * S_DIM;
        else if (row < 1152) src = Whf + (size_t)(row - 1088) * S_DIM;
        else if (row < 1216) src = Wv1 + (size_t)(row - 1152) * S_DIM;
        if (src) {
            float4 v = reinterpret_cast<const float4*>(src)[qc];
            o = ushort4{ f2bf(v.x), f2bf(v.y), f2bf(v.z), f2bf(v.w) };
        }
        reinterpret_cast<ushort4*>(Bbf)[q] = o;
    }
}

// ---------------------------------------------------------------- K1: MFMA GEMM
// *** INSTRUMENTED this round: K-loop repeated 4x (acc reset per rep, output
// identical) so the dispatch surfaces in rocprof top-5 above the 41us fills.
#define GEMM_REPS 4

#define GL2L16(g, l) __builtin_amdgcn_global_load_lds(                        \
    (const __attribute__((address_space(1))) void*)(g),                      \
    (__attribute__((address_space(3))) void*)(l), 16, 0, 0)

__global__ __launch_bounds__(256, 2) void gemm_bf16(
    const unsigned short* __restrict__ Abf,
    const unsigned short* __restrict__ Bbf,
    const float* __restrict__ bh1, const float* __restrict__ bb1,
    const float* __restrict__ bhf, const float* __restrict__ bv1,
    unsigned short* __restrict__ w1_bf,
    float* __restrict__ b1_all, float* __restrict__ wf_all,
    float* __restrict__ hv_all)
{
    // [buf][row][32], 64 B/row; buf stride 4096 shorts = 8 KB
    __shared__ short As[2 * 128 * 32];
    __shared__ short Bs[2 * 128 * 32];

    const int tid  = threadIdx.x;
    const int lane = tid & 63;
    const int wave = tid >> 6;
    const int n0 = blockIdx.x * 128;
    const int j0 = blockIdx.y * 128;

    const int gchunk = (lane & 3) ^ ((lane >> 3) & 3);
    const int srow   = wave * 32 + (lane >> 2);
    const unsigned short* gA0 = Abf + (size_t)(n0 + srow) * S_DIM + gchunk * 8;
    const unsigned short* gA1 = gA0 + 16 * S_DIM;
    const unsigned short* gB0 = Bbf + (size_t)(j0 + srow) * S_DIM + gchunk * 8;
    const unsigned short* gB1 = gB0 + 16 * S_DIM;
    short* lA0 = &As[(wave * 32) * 32];
    short* lA1 = &As[(wave * 32 + 16) * 32];
    short* lB0 = &Bs[(wave * 32) * 32];
    short* lB1 = &Bs[(wave * 32 + 16) * 32];

    const int wr = wave >> 1, wc = wave & 1;
    const int l16 = lane & 15, lk = lane >> 4;
    const int rchunk = lk ^ ((l16 >> 1) & 3);
    const short* pA = &As[(wr * 64 + l16) * 32 + rchunk * 8];
    const short* pB = &Bs[(wc * 64 + l16) * 32 + rchunk * 8];

    const f32x4 zero = {0.f, 0.f, 0.f, 0.f};
    f32x4 acc[4][4];

#define STAGE(bi, t) do {                                                     \
        GL2L16(gA0 + (size_t)(t) * 32, lA0 + (bi) * 4096);                    \
        GL2L16(gA1 + (size_t)(t) * 32, lA1 + (bi) * 4096);                    \
        GL2L16(gB0 + (size_t)(t) * 32, lB0 + (bi) * 4096);                    \
        GL2L16(gB1 + (size_t)(t) * 32, lB1 + (bi) * 4096);                    \
    } while (0)

#define COMPUTE(bi) do {                                                      \
        bf16x8 a_[4], b_[4];                                                  \
        _Pragma("unroll")                                                     \
        for (int m = 0; m < 4; ++m)                                           \
            a_[m] = *reinterpret_cast<const bf16x8*>(pA + (bi) * 4096 + m * 512); \
        _Pragma("unroll")                                                     \
        for (int n = 0; n < 4; ++n)                                           \
            b_[n] = *reinterpret_cast<const bf16x8*>(pB + (bi) * 4096 + n * 512); \
        __builtin_amdgcn_s_setprio(1);                                        \
        _Pragma("unroll")                                                     \
        for (int m = 0; m < 4; ++m)                                           \
            _Pragma("unroll")                                                 \
            for (int n = 0; n < 4; ++n)                                       \
                acc[m][n] = __builtin_amdgcn_mfma_f32_16x16x32_bf16(          \
                    a_[m], b_[n], acc[m][n], 0, 0, 0);                        \
        __builtin_amdgcn_s_setprio(0);                                        \
    } while (0)

#pragma unroll 1
    for (int rep = 0; rep < GEMM_REPS; ++rep) {
#pragma unroll
        for (int m = 0; m < 4; ++m)
#pragma unroll
            for (int n = 0; n < 4; ++n) acc[m][n] = zero;

        STAGE(0, 0);
        __syncthreads();
#pragma unroll 1
        for (int ks = 0; ks < 16; ks += 2) {
            STAGE(1, ks + 1);
            COMPUTE(0);
            __syncthreads();
            if (ks + 2 < 16) STAGE(0, ks + 2);
            COMPUTE(1);
            __syncthreads();
        }
    }
#undef STAGE
#undef COMPUTE

    const int orow = n0 + wr * 64 + lk * 4;
    const int ocol = j0 + wc * 64 + l16;
#pragma unroll
    for (int m = 0; m < 4; ++m) {
#pragma unroll
        for (int n = 0; n < 4; ++n) {
            int j = ocol + n * 16;
#pragma unroll
            for (int r = 0; r < 4; ++r) {
                int row = orow + m * 16 + r;
                float val = acc[m][n][r];
                if (j < 1024)
                    w1_bf[(size_t)row * 1024 + j] = f2bf(val + bh1[j]);
                else if (j < 1088)
                    b1_all[(size_t)row * 64 + (j - 1024)] = val + bb1[j - 1024];
                else if (j < 1152)
                    wf_all[(size_t)row * 64 + (j - 1088)] = val + bhf[j - 1088];
                else if (j < J_DIM)
                    hv_all[(size_t)row * 64 + (j - 1152)] = val + bv1[j - 1152];
            }
        }
    }
}

// ---------------------------------------------------------------- K2: mixer
// Rewritten: 1 wave per sample, lane l owns 5 consecutive m = [5l, 5l+5)
// (all sharing agent i = l>>2). LDS reads vectorized f32x4 and amortized
// over the 5 m's. Branchless elu: elu(x) = max(x,0) + exp2(min(x*log2e,0)) - 1,
// with log2e pre-folded into delta/bias and ln2 folded into wf.
struct WaveLds {
    float w1f[A_DIM][68];   // padded: bank = (4*i + e) % 32 -> 2-way max
    float qrow[M_DIM];
    float bd2[E_DIM];       // (base + b1) * log2e
    float wfl[E_DIM];       // wf * ln2
    float wfe[E_DIM];       // wf
    float qts[A_DIM];
};

__global__ __launch_bounds__(256) void mixer(
    const float* __restrict__ q_agents, const int* __restrict__ actions,
    const unsigned short* __restrict__ w1_bf, const float* __restrict__ b1_all,
    const float* __restrict__ wf_all, const float* __restrict__ hv_all,
    const float* __restrict__ Wv2, const float* __restrict__ bv2,
    float* __restrict__ out)
{
    __shared__ WaveLds L[4];
    const int w = threadIdx.x >> 6;
    const int l = threadIdx.x & 63;
    const int n = blockIdx.x * 4 + w;
    WaveLds& Q = L[w];

    // ---- phase A: stage ----
#pragma unroll
    for (int j = 0; j < 5; ++j)
        Q.qrow[l + 64 * j] = q_agents[(size_t)n * M_DIM + l + 64 * j];
    float b1e  = b1_all[(size_t)n * 64 + l];
    float wfe_ = wf_all[(size_t)n * 64 + l];
    float hve  = hv_all[(size_t)n * 64 + l];
    float wv2e = Wv2[l];
    ushort8 u0 = *reinterpret_cast<const ushort8*>(w1_bf + (size_t)n * 1024 + l * 16);
    ushort8 u1 = *reinterpret_cast<const ushort8*>(w1_bf + (size_t)n * 1024 + l * 16 + 8);
    {
        int a = l >> 2, c0 = (l & 3) * 16;
#pragma unroll
        for (int q = 0; q < 8; ++q) Q.w1f[a][c0 + q]     = bf2f((unsigned short)u0[q]);
#pragma unroll
        for (int q = 0; q < 8; ++q) Q.w1f[a][c0 + 8 + q] = bf2f((unsigned short)u1[q]);
    }
    int act = (l < A_DIM) ? actions[n * A_DIM + l] : 0;
    __syncthreads();
    if (l < A_DIM) Q.qts[l] = Q.qrow[l * ACT_DIM + act];
    __syncthreads();

    // v and sum(wf), full-wave butterflies (all lanes end with the sum)
    float vp = fmaxf(hve, 0.f) * wv2e;
    float sw = wfe_;
#pragma unroll
    for (int off = 32; off; off >>= 1) {
        vp += __shfl_xor(vp, off, 64);
        sw += __shfl_xor(sw, off, 64);
    }
    float vfin = vp + bv2[0];

    // base[e=l] = sum_a qt[a] * w1[a,e]
    float base = 0.f;
#pragma unroll
    for (int a = 0; a < A_DIM; ++a) base = fmaf(Q.qts[a], Q.w1f[a][l], base);
    Q.bd2[l] = (base + b1e) * LOG2E;
    Q.wfl[l] = wfe_ * LN2;
    Q.wfe[l] = wfe_;
    __syncthreads();

    // ---- phase B: 5 m's per lane, e-chunked ----
    const int i = l >> 2;
    const float qti = Q.qts[i];
    float d2[5];
#pragma unroll
    for (int k = 0; k < 5; ++k)
        d2[k] = (Q.qrow[i * ACT_DIM + 5 * (l & 3) + k] - qti) * LOG2E;

    float a1[5] = {0, 0, 0, 0, 0}, a2[5] = {0, 0, 0, 0, 0};
#pragma unroll 2
    for (int e0 = 0; e0 < E_DIM; e0 += 4) {
        f32x4 w4 = *reinterpret_cast<const f32x4*>(&Q.w1f[i][e0]);
        f32x4 b4 = *reinterpret_cast<const f32x4*>(&Q.bd2[e0]);
        f32x4 l4 = *reinterpret_cast<const f32x4*>(&Q.wfl[e0]);
        f32x4 f4 = *reinterpret_cast<const f32x4*>(&Q.wfe[e0]);
#pragma unroll
        for (int j = 0; j < 4; ++j) {
#pragma unroll
            for (int k = 0; k < 5; ++k) {
                float pre2 = fmaf(d2[k], w4[j], b4[j]);          // (pre)*log2e
                a1[k] = fmaf(fmaxf(pre2, 0.f), l4[j], a1[k]);    // linear part
                a2[k] = fmaf(exp2f(fminf(pre2, 0.f)), f4[j], a2[k]); // exp part
            }
        }
    }
#pragma unroll
    for (int k = 0; k < 5; ++k)
        out[(size_t)n * M_DIM + 5 * l + k] = a1[k] + a2[k] - sw + vfin;
}

extern "C" void kernel_launch(void* const* d_in, const int* in_sizes, int n_in,
                              void* d_out, int out_size, void* d_ws, size_t ws_size,
                              hipStream_t stream)
{
    const float* q_agents = (const float*)d_in[0];
    const int*   actions  = (const int*)d_in[1];
    const float* state    = (const float*)d_in[2];
    const float* Wh1 = (const float*)d_in[3];
    const float* bh1 = (const float*)d_in[4];
    const float* Wb1 = (const float*)d_in[5];
    const float* bb1 = (const float*)d_in[6];
    const float* Whf = (const float*)d_in[7];
    const float* bhf = (const float*)d_in[8];
    const float* Wv1 = (const float*)d_in[9];
    const float* bv1 = (const float*)d_in[10];
    const float* Wv2 = (const float*)d_in[11];
    const float* bv2 = (const float*)d_in[12];
    float* out = (float*)d_out;

    char* ws = (char*)d_ws;
    unsigned short* Abf   = (unsigned short*)ws;                        // 4 MB
    unsigned short* Bbf   = (unsigned short*)(ws + 4194304);            // 1.31 MB
    unsigned short* w1_bf = (unsigned short*)(ws + 5505024);            // 8 MB
    float* b1_all = (float*)(ws + 5505024 + 8388608);                   // 1 MB
    float* wf_all = b1_all + (size_t)N_SAMPLES * 64;
    float* hv_all = wf_all + (size_t)N_SAMPLES * 64;

    const int total_quads = N_SAMPLES * S_DIM / 4 + JPAD * S_DIM / 4;   // 688128
    hipLaunchKernelGGL(cvt_bf16, dim3((total_quads + 255) / 256), dim3(256), 0, stream,
                       state, Wh1, Wb1, Whf, Wv1, Abf, Bbf);

    dim3 g1(N_SAMPLES / 128, JPAD / 128);
    hipLaunchKernelGGL(gemm_bf16, g1, dim3(256), 0, stream,
                       Abf, Bbf, bh1, bb1, bhf, bv1,
                       w1_bf, b1_all, wf_all, hv_all);

    hipLaunchKernelGGL(mixer, dim3(N_SAMPLES / 4), dim3(256), 0, stream,
                       q_agents, actions, w1_bf, b1_all, wf_all, hv_all,
                       Wv2, bv2, out);
}

// Round 5
// 59.778 us; speedup vs baseline: 1.4034x; 1.4034x over previous
//
#include <hip/hip_runtime.h>
#include <math.h>
#include <stdint.h>

#define N_SAMPLES 4096
#define S_DIM 512
#define A_DIM 16
#define ACT_DIM 20
#define E_DIM 64
#define M_DIM 320      // A*ACT
#define J_DIM 1216     // 1024 (W_h1) + 64 (W_b1) + 64 (W_hf) + 64 (W_v1)
#define JPAD 1280      // padded to 10 * 128 so staging never goes OOB

#define LOG2E 1.44269504088896f
#define LN2   0.69314718055995f

using bf16x8  = __attribute__((ext_vector_type(8))) short;
using f32x4   = __attribute__((ext_vector_type(4))) float;
using ushort8 = __attribute__((ext_vector_type(8))) unsigned short;

__device__ __forceinline__ unsigned short f2bf(float x) {  // RNE f32 -> bf16
    uint32_t u = __float_as_uint(x);
    u += 0x7fffu + ((u >> 16) & 1u);
    return (unsigned short)(u >> 16);
}
__device__ __forceinline__ float bf2f(unsigned short u) {
    return __uint_as_float(((uint32_t)u) << 16);
}

// ---------------------------------------------------------------- K0: convert B only
// Bbf[1280][512] <- {Wh1,Wb1,Whf,Wv1, zeros}. A (state) is converted inline in K1.
__global__ __launch_bounds__(256) void cvt_bf16(
    const float* __restrict__ Wh1, const float* __restrict__ Wb1,
    const float* __restrict__ Whf, const float* __restrict__ Wv1,
    unsigned short* __restrict__ Bbf)
{
    const int B_QUADS = JPAD * S_DIM / 4;        // 163840
    int q = blockIdx.x * 256 + threadIdx.x;
    if (q >= B_QUADS) return;
    int row = q >> 7;          // 128 quads per 512-elem row
    int qc  = q & 127;
    ushort4 o = {0, 0, 0, 0};
    const float* src = nullptr;
    if (row < 1024)      src = Wh1 + (size_t)row * S_DIM;
    else if (row < 1088) src = Wb1 + (size_t)(row - 1024) * S_DIM;
    else if (row < 1152) src = Whf + (size_t)(row - 1088) * S_DIM;
    else if (row < 1216) src = Wv1 + (size_t)(row - 1152) * S_DIM;
    if (src) {
        float4 v = reinterpret_cast<const float4*>(src)[qc];
        o = ushort4{ f2bf(v.x), f2bf(v.y), f2bf(v.z), f2bf(v.w) };
    }
    reinterpret_cast<ushort4*>(Bbf)[q] = o;
}

// ---------------------------------------------------------------- K1: MFMA GEMM
// BM=64 x BN=128, BK=32 -> grid 64x10 = 640 blocks (2.5 blocks/CU).
// B staged via global_load_lds from precomputed bf16; A staged via
// reg-load f32 state -> f2bf -> ds_write_b128 (same linear LDS layout).
#define GL2L16(g, l) __builtin_amdgcn_global_load_lds(                        \
    (const __attribute__((address_space(1))) void*)(g),                      \
    (__attribute__((address_space(3))) void*)(l), 16, 0, 0)

__global__ __launch_bounds__(256, 4) void gemm_bf16(
    const float* __restrict__ Sf,
    const unsigned short* __restrict__ Bbf,
    const float* __restrict__ bh1, const float* __restrict__ bb1,
    const float* __restrict__ bhf, const float* __restrict__ bv1,
    unsigned short* __restrict__ w1_bf,
    float* __restrict__ b1_all, float* __restrict__ wf_all,
    float* __restrict__ hv_all)
{
    // [buf][row][32]; A buf stride 2048 shorts (4 KB), B buf stride 4096 (8 KB)
    __shared__ short As[2 * 64 * 32];
    __shared__ short Bs[2 * 128 * 32];

    const int tid  = threadIdx.x;
    const int lane = tid & 63;
    const int wave = tid >> 6;
    const int n0 = blockIdx.x * 64;
    const int j0 = blockIdx.y * 128;

    // swizzle: LDS[row][c] holds global chunk c ^ ((row>>1)&3)  (8-short chunks)
    const int gchunk = (lane & 3) ^ ((lane >> 3) & 3);

    // A: wave stages rows [wave*16, wave*16+16) from f32 state
    const float* gAf = Sf + (size_t)(n0 + wave * 16 + (lane >> 2)) * S_DIM + gchunk * 8;
    short* dstA = &As[wave * 512 + lane * 8];      // linear lane order, 16B/lane

    // B: wave stages rows [wave*32, wave*32+32) via 2x global_load_lds
    const int srowB = wave * 32 + (lane >> 2);
    const unsigned short* gB0 = Bbf + (size_t)(j0 + srowB) * S_DIM + gchunk * 8;
    const unsigned short* gB1 = gB0 + 16 * S_DIM;
    short* lB0 = &Bs[(wave * 32) * 32];
    short* lB1 = lB0 + 512;

    // fragments: wave (wr,wc) owns 32x64; 2x4 16x16x32 frags
    const int wr = wave >> 1, wc = wave & 1;
    const int l16 = lane & 15, lk = lane >> 4;
    const int rchunk = lk ^ ((l16 >> 1) & 3);
    const short* pA = &As[(wr * 32 + l16) * 32 + rchunk * 8];
    const short* pB = &Bs[(wc * 64 + l16) * 32 + rchunk * 8];

    f32x4 acc[2][4] = {};

#define STAGE_B(bi, t) do {                                                   \
        GL2L16(gB0 + (size_t)(t) * 32, lB0 + (bi) * 4096);                    \
        GL2L16(gB1 + (size_t)(t) * 32, lB1 + (bi) * 4096);                    \
    } while (0)

#define ST_A(bi, v0, v1) do {                                                 \
        bf16x8 o_;                                                            \
        o_[0] = (short)f2bf((v0).x); o_[1] = (short)f2bf((v0).y);             \
        o_[2] = (short)f2bf((v0).z); o_[3] = (short)f2bf((v0).w);             \
        o_[4] = (short)f2bf((v1).x); o_[5] = (short)f2bf((v1).y);             \
        o_[6] = (short)f2bf((v1).z); o_[7] = (short)f2bf((v1).w);             \
        *reinterpret_cast<bf16x8*>(dstA + (bi) * 2048) = o_;                  \
    } while (0)

#define COMPUTE(bi) do {                                                      \
        bf16x8 a_[2], b_[4];                                                  \
        _Pragma("unroll")                                                     \
        for (int m = 0; m < 2; ++m)                                           \
            a_[m] = *reinterpret_cast<const bf16x8*>(pA + (bi) * 2048 + m * 512); \
        _Pragma("unroll")                                                     \
        for (int n = 0; n < 4; ++n)                                           \
            b_[n] = *reinterpret_cast<const bf16x8*>(pB + (bi) * 4096 + n * 512); \
        __builtin_amdgcn_s_setprio(1);                                        \
        _Pragma("unroll")                                                     \
        for (int m = 0; m < 2; ++m)                                           \
            _Pragma("unroll")                                                 \
            for (int n = 0; n < 4; ++n)                                       \
                acc[m][n] = __builtin_amdgcn_mfma_f32_16x16x32_bf16(          \
                    a_[m], b_[n], acc[m][n], 0, 0, 0);                        \
        __builtin_amdgcn_s_setprio(0);                                        \
    } while (0)

    // prologue: tile 0 -> buf0
    {
        float4 a0 = *reinterpret_cast<const float4*>(gAf);
        float4 a1 = *reinterpret_cast<const float4*>(gAf + 4);
        STAGE_B(0, 0);
        ST_A(0, a0, a1);
    }
    __syncthreads();

#pragma unroll 1
    for (int ks = 0; ks < 16; ks += 2) {
        float4 p0 = *reinterpret_cast<const float4*>(gAf + (size_t)(ks + 1) * 32);
        float4 p1 = *reinterpret_cast<const float4*>(gAf + (size_t)(ks + 1) * 32 + 4);
        STAGE_B(1, ks + 1);        // next-tile B DMA in flight across compute
        COMPUTE(0);
        ST_A(1, p0, p1);           // write-late: vmcnt covered by COMPUTE
        __syncthreads();
        float4 q0, q1;
        if (ks + 2 < 16) {
            q0 = *reinterpret_cast<const float4*>(gAf + (size_t)(ks + 2) * 32);
            q1 = *reinterpret_cast<const float4*>(gAf + (size_t)(ks + 2) * 32 + 4);
            STAGE_B(0, ks + 2);
        }
        COMPUTE(1);
        if (ks + 2 < 16) ST_A(0, q0, q1);
        __syncthreads();
    }
#undef STAGE_B
#undef ST_A
#undef COMPUTE

    // epilogue: C/D layout col=lane&15, row=(lane>>4)*4+reg (m89-verified)
    const int orow = n0 + wr * 32 + lk * 4;
    const int ocol = j0 + wc * 64 + l16;
#pragma unroll
    for (int m = 0; m < 2; ++m) {
#pragma unroll
        for (int n = 0; n < 4; ++n) {
            int j = ocol + n * 16;
#pragma unroll
            for (int r = 0; r < 4; ++r) {
                int row = orow + m * 16 + r;
                float val = acc[m][n][r];
                if (j < 1024)
                    w1_bf[(size_t)row * 1024 + j] = f2bf(val + bh1[j]);
                else if (j < 1088)
                    b1_all[(size_t)row * 64 + (j - 1024)] = val + bb1[j - 1024];
                else if (j < 1152)
                    wf_all[(size_t)row * 64 + (j - 1088)] = val + bhf[j - 1088];
                else if (j < J_DIM)
                    hv_all[(size_t)row * 64 + (j - 1152)] = val + bv1[j - 1152];
            }
        }
    }
}

// ---------------------------------------------------------------- K2: mixer
// 1 wave per sample; lane l owns 5 consecutive m = [5l, 5l+5) (one agent i=l>>2).
// Branchless elu via exp2; log2e folded into delta/bias, ln2 into wf.
struct WaveLds {
    float w1f[A_DIM][68];
    float qrow[M_DIM];
    float bd2[E_DIM];       // (base + b1) * log2e
    float wfl[E_DIM];       // wf * ln2
    float wfe[E_DIM];       // wf
    float qts[A_DIM];
};

__global__ __launch_bounds__(256) void mixer(
    const float* __restrict__ q_agents, const int* __restrict__ actions,
    const unsigned short* __restrict__ w1_bf, const float* __restrict__ b1_all,
    const float* __restrict__ wf_all, const float* __restrict__ hv_all,
    const float* __restrict__ Wv2, const float* __restrict__ bv2,
    float* __restrict__ out)
{
    __shared__ WaveLds L[4];
    const int w = threadIdx.x >> 6;
    const int l = threadIdx.x & 63;
    const int n = blockIdx.x * 4 + w;
    WaveLds& Q = L[w];

#pragma unroll
    for (int j = 0; j < 5; ++j)
        Q.qrow[l + 64 * j] = q_agents[(size_t)n * M_DIM + l + 64 * j];
    float b1e  = b1_all[(size_t)n * 64 + l];
    float wfe_ = wf_all[(size_t)n * 64 + l];
    float hve  = hv_all[(size_t)n * 64 + l];
    float wv2e = Wv2[l];
    ushort8 u0 = *reinterpret_cast<const ushort8*>(w1_bf + (size_t)n * 1024 + l * 16);
    ushort8 u1 = *reinterpret_cast<const ushort8*>(w1_bf + (size_t)n * 1024 + l * 16 + 8);
    {
        int a = l >> 2, c0 = (l & 3) * 16;
#pragma unroll
        for (int q = 0; q < 8; ++q) Q.w1f[a][c0 + q]     = bf2f((unsigned short)u0[q]);
#pragma unroll
        for (int q = 0; q < 8; ++q) Q.w1f[a][c0 + 8 + q] = bf2f((unsigned short)u1[q]);
    }
    int act = (l < A_DIM) ? actions[n * A_DIM + l] : 0;
    __syncthreads();
    if (l < A_DIM) Q.qts[l] = Q.qrow[l * ACT_DIM + act];
    __syncthreads();

    float vp = fmaxf(hve, 0.f) * wv2e;
    float sw = wfe_;
#pragma unroll
    for (int off = 32; off; off >>= 1) {
        vp += __shfl_xor(vp, off, 64);
        sw += __shfl_xor(sw, off, 64);
    }
    float vfin = vp + bv2[0];

    float base = 0.f;
#pragma unroll
    for (int a = 0; a < A_DIM; ++a) base = fmaf(Q.qts[a], Q.w1f[a][l], base);
    Q.bd2[l] = (base + b1e) * LOG2E;
    Q.wfl[l] = wfe_ * LN2;
    Q.wfe[l] = wfe_;
    __syncthreads();

    const int i = l >> 2;
    const float qti = Q.qts[i];
    float d2[5];
#pragma unroll
    for (int k = 0; k < 5; ++k)
        d2[k] = (Q.qrow[i * ACT_DIM + 5 * (l & 3) + k] - qti) * LOG2E;

    float a1[5] = {0, 0, 0, 0, 0}, a2[5] = {0, 0, 0, 0, 0};
#pragma unroll 2
    for (int e0 = 0; e0 < E_DIM; e0 += 4) {
        f32x4 w4 = *reinterpret_cast<const f32x4*>(&Q.w1f[i][e0]);
        f32x4 b4 = *reinterpret_cast<const f32x4*>(&Q.bd2[e0]);
        f32x4 l4 = *reinterpret_cast<const f32x4*>(&Q.wfl[e0]);
        f32x4 f4 = *reinterpret_cast<const f32x4*>(&Q.wfe[e0]);
#pragma unroll
        for (int j = 0; j < 4; ++j) {
#pragma unroll
            for (int k = 0; k < 5; ++k) {
                float pre2 = fmaf(d2[k], w4[j], b4[j]);
                a1[k] = fmaf(fmaxf(pre2, 0.f), l4[j], a1[k]);
                a2[k] = fmaf(exp2f(fminf(pre2, 0.f)), f4[j], a2[k]);
            }
        }
    }
#pragma unroll
    for (int k = 0; k < 5; ++k)
        out[(size_t)n * M_DIM + 5 * l + k] = a1[k] + a2[k] - sw + vfin;
}

extern "C" void kernel_launch(void* const* d_in, const int* in_sizes, int n_in,
                              void* d_out, int out_size, void* d_ws, size_t ws_size,
                              hipStream_t stream)
{
    const float* q_agents = (const float*)d_in[0];
    const int*   actions  = (const int*)d_in[1];
    const float* state    = (const float*)d_in[2];
    const float* Wh1 = (const float*)d_in[3];
    const float* bh1 = (const float*)d_in[4];
    const float* Wb1 = (const float*)d_in[5];
    const float* bb1 = (const float*)d_in[6];
    const float* Whf = (const float*)d_in[7];
    const float* bhf = (const float*)d_in[8];
    const float* Wv1 = (const float*)d_in[9];
    const float* bv1 = (const float*)d_in[10];
    const float* Wv2 = (const float*)d_in[11];
    const float* bv2 = (const float*)d_in[12];
    float* out = (float*)d_out;

    char* ws = (char*)d_ws;
    unsigned short* Bbf   = (unsigned short*)ws;                 // 1280*512*2 = 1.31 MB
    unsigned short* w1_bf = (unsigned short*)(ws + 1310720);     // 4096*1024*2 = 8 MB
    float* b1_all = (float*)(ws + 1310720 + 8388608);            // 4096*64*4 = 1 MB
    float* wf_all = b1_all + (size_t)N_SAMPLES * 64;
    float* hv_all = wf_all + (size_t)N_SAMPLES * 64;

    const int b_quads = JPAD * S_DIM / 4;                        // 163840
    hipLaunchKernelGGL(cvt_bf16, dim3((b_quads + 255) / 256), dim3(256), 0, stream,
                       Wh1, Wb1, Whf, Wv1, Bbf);

    dim3 g1(N_SAMPLES / 64, JPAD / 128);                         // 64 x 10
    hipLaunchKernelGGL(gemm_bf16, g1, dim3(256), 0, stream,
                       state, Bbf, bh1, bb1, bhf, bv1,
                       w1_bf, b1_all, wf_all, hv_all);

    hipLaunchKernelGGL(mixer, dim3(N_SAMPLES / 4), dim3(256), 0, stream,
                       q_agents, actions, w1_bf, b1_all, wf_all, hv_all,
                       Wv2, bv2, out);
}